// Round 12
// baseline (596.694 us; speedup 1.0000x reference)
//
#include <hip/hip_runtime.h>
#include <math.h>

#define BS 256
#define LQ 256
#define KN 64
#define BH 512
#define SUB_IN 1537

typedef __attribute__((ext_vector_type(8))) short bf16x8;
typedef __attribute__((ext_vector_type(4))) float f32x4;

__device__ __forceinline__ float clip15(float x) {
  return fminf(fmaxf(x, -15.f), 15.f);
}
__device__ __forceinline__ short f2bf(float f) {
  unsigned u = __float_as_uint(f);
  u = u + 0x7fffu + ((u >> 16) & 1u);
  return (short)(u >> 16);
}
__device__ __forceinline__ float bf2f(short s) {
  return __uint_as_float(((unsigned)(unsigned short)s) << 16);
}

// XOR swizzle on the 16B slot within each 128B LDS row (proven R2-R11)
#define SWZ(row, byte) ((byte) ^ (((((row) ^ ((row) >> 3)) & 7)) << 4))

// async global->LDS, 16B per lane; LDS dest = wave-uniform base + lane*16
__device__ __forceinline__ void gl_lds16(const short* g, short* l) {
  __builtin_amdgcn_global_load_lds(
      (const __attribute__((address_space(1))) void*)g,
      (__attribute__((address_space(3))) void*)l, 16, 0, 0);
}

// ---------------- prep kernels ----------------

// one pass over node: node_bf, Cw_o = node*wm_o, Cw_a = node*wm_a, cw_o/cw_a rowdots
__global__ void k_cvtC2(const float* __restrict__ X,
                        const float* __restrict__ wc_o, const float* __restrict__ wc_a,
                        const float* __restrict__ wm_o, const float* __restrict__ wm_a,
                        short* __restrict__ Xbf, short* __restrict__ Xw_o,
                        short* __restrict__ Xw_a,
                        float* __restrict__ rd_o, float* __restrict__ rd_a) {
  int row = blockIdx.x * 4 + (threadIdx.x >> 6);
  int lane = threadIdx.x & 63;
  const float* x = X + (size_t)row * BH + lane * 8;
  f32x4 v0 = *(const f32x4*)x;
  f32x4 v1 = *(const f32x4*)(x + 4);
  f32x4 co0 = *(const f32x4*)(wc_o + lane * 8);
  f32x4 co1 = *(const f32x4*)(wc_o + lane * 8 + 4);
  f32x4 ca0 = *(const f32x4*)(wc_a + lane * 8);
  f32x4 ca1 = *(const f32x4*)(wc_a + lane * 8 + 4);
  float so = v0[0] * co0[0] + v0[1] * co0[1] + v0[2] * co0[2] + v0[3] * co0[3] +
             v1[0] * co1[0] + v1[1] * co1[1] + v1[2] * co1[2] + v1[3] * co1[3];
  float sa = v0[0] * ca0[0] + v0[1] * ca0[1] + v0[2] * ca0[2] + v0[3] * ca0[3] +
             v1[0] * ca1[0] + v1[1] * ca1[1] + v1[2] * ca1[2] + v1[3] * ca1[3];
#pragma unroll
  for (int off = 32; off; off >>= 1) { so += __shfl_down(so, off); sa += __shfl_down(sa, off); }
  if (lane == 0) { rd_o[row] = so; rd_a[row] = sa; }
  f32x4 mo0 = *(const f32x4*)(wm_o + lane * 8);
  f32x4 mo1 = *(const f32x4*)(wm_o + lane * 8 + 4);
  f32x4 ma0 = *(const f32x4*)(wm_a + lane * 8);
  f32x4 ma1 = *(const f32x4*)(wm_a + lane * 8 + 4);
  bf16x8 ob, oo, oa;
#pragma unroll
  for (int j = 0; j < 4; ++j) {
    ob[j] = f2bf(v0[j]);          ob[4 + j] = f2bf(v1[j]);
    oo[j] = f2bf(v0[j] * mo0[j]); oo[4 + j] = f2bf(v1[j] * mo1[j]);
    oa[j] = f2bf(v0[j] * ma0[j]); oa[4 + j] = f2bf(v1[j] * ma1[j]);
  }
  size_t gi = (size_t)row * BH + lane * 8;
  *(bf16x8*)(Xbf + gi) = ob;
  *(bf16x8*)(Xw_o + gi) = oo;
  *(bf16x8*)(Xw_a + gi) = oa;
}

// prjT[head][n][k] = bf16(prj_head[k][n]); k=2048, n=512
__global__ void k_prjT(const float* __restrict__ prj_o, const float* __restrict__ prj_a,
                       short* __restrict__ prjT) {
  __shared__ float t[32][33];
  int k0 = blockIdx.x * 32, n0 = blockIdx.y * 32, head = blockIdx.z;
  const float* prj = head ? prj_a : prj_o;
  short* dst = prjT + (size_t)head * BH * 2048;
  int x = threadIdx.x & 31, y = threadIdx.x >> 5;  // 32x8
  for (int yy = y; yy < 32; yy += 8)
    t[yy][x] = prj[(size_t)(k0 + yy) * BH + n0 + x];
  __syncthreads();
  for (int yy = y; yy < 32; yy += 8)
    dst[(size_t)(n0 + yy) * 2048 + k0 + x] = f2bf(t[x][yy]);
}

// WT[kb][o][s] = bf16(W[kb][s][o]); s<1536 only
__global__ void k_WT(const float* __restrict__ W, short* __restrict__ WT) {
  __shared__ float t[32][33];
  int s0 = blockIdx.x * 32, o0 = blockIdx.y * 32, kb = blockIdx.z;
  const float* Wk = W + (size_t)kb * SUB_IN * BH;
  int x = threadIdx.x & 31, y = threadIdx.x >> 5;
  for (int yy = y; yy < 32; yy += 8)
    t[yy][x] = Wk[(size_t)(s0 + yy) * BH + o0 + x];
  __syncthreads();
  for (int yy = y; yy < 32; yy += 8)
    WT[((size_t)kb * BH + o0 + yy) * 1536 + s0 + x] = f2bf(t[x][yy]);
}

// ---------------- staging helpers ----------------

__device__ __forceinline__ void stage_nat(const short* __restrict__ src, size_t ld,
                                          short* As, int tid) {
  int kl = (tid & 15) * 4;
#pragma unroll
  for (int it = 0; it < 4; ++it) {
    int row = (tid >> 4) + it * 16;
    short4 v = *(const short4*)(src + (size_t)row * ld + kl);
    *(short4*)((char*)As + SWZ(row, row * 128 + kl * 2)) = v;
  }
}

__device__ __forceinline__ void stage_tr(const short* __restrict__ src, size_t ld,
                                         short* Bs, int tid) {
  int n0 = (tid & 15) * 4;
  int k0 = (tid >> 4) * 4;
  short4 r0 = *(const short4*)(src + (size_t)(k0 + 0) * ld + n0);
  short4 r1 = *(const short4*)(src + (size_t)(k0 + 1) * ld + n0);
  short4 r2 = *(const short4*)(src + (size_t)(k0 + 2) * ld + n0);
  short4 r3 = *(const short4*)(src + (size_t)(k0 + 3) * ld + n0);
  *(short4*)((char*)Bs + SWZ(n0 + 0, (n0 + 0) * 128 + k0 * 2)) = make_short4(r0.x, r1.x, r2.x, r3.x);
  *(short4*)((char*)Bs + SWZ(n0 + 1, (n0 + 1) * 128 + k0 * 2)) = make_short4(r0.y, r1.y, r2.y, r3.y);
  *(short4*)((char*)Bs + SWZ(n0 + 2, (n0 + 2) * 128 + k0 * 2)) = make_short4(r0.z, r1.z, r2.z, r3.z);
  *(short4*)((char*)Bs + SWZ(n0 + 3, (n0 + 3) * 128 + k0 * 2)) = make_short4(r0.w, r1.w, r2.w, r3.w);
}

// transposed: f32 source [k][n] (stride ld) -> Bs[n][k] with convert (proven R2)
__device__ __forceinline__ void stage_tr_f32(const float* __restrict__ src, size_t ld,
                                             short* Bs, int tid) {
  int n0 = (tid & 15) * 4;
  int k0 = (tid >> 4) * 4;
  f32x4 r0 = *(const f32x4*)(src + (size_t)(k0 + 0) * ld + n0);
  f32x4 r1 = *(const f32x4*)(src + (size_t)(k0 + 1) * ld + n0);
  f32x4 r2 = *(const f32x4*)(src + (size_t)(k0 + 2) * ld + n0);
  f32x4 r3 = *(const f32x4*)(src + (size_t)(k0 + 3) * ld + n0);
#pragma unroll
  for (int j = 0; j < 4; ++j) {
    int n = n0 + j;
    *(short4*)((char*)Bs + SWZ(n, n * 128 + k0 * 2)) =
        make_short4(f2bf(r0[j]), f2bf(r1[j]), f2bf(r2[j]), f2bf(r3[j]));
  }
}

__device__ __forceinline__ void mfma64(const short* As, const short* Bs,
                                       f32x4 acc[4], int lane, int m0) {
#pragma unroll
  for (int kb = 0; kb < 2; ++kb) {
    int k16 = kb * 32 + (lane >> 4) * 8;
    int arow = m0 + (lane & 15);
    bf16x8 af = *(const bf16x8*)((const char*)As + SWZ(arow, arow * 128 + k16 * 2));
#pragma unroll
    for (int f = 0; f < 4; ++f) {
      int nrow = f * 16 + (lane & 15);
      bf16x8 bfr = *(const bf16x8*)((const char*)Bs + SWZ(nrow, nrow * 128 + k16 * 2));
      acc[f] = __builtin_amdgcn_mfma_f32_16x16x32_bf16(af, bfr, acc[f], 0, 0, 0);
    }
  }
}

// ---------------- fused score + dual softmax + inline qw rowdot ----------------
__global__ void k_score2(const short* __restrict__ Cw_o, const short* __restrict__ Cw_a,
                         const float* __restrict__ obs, const float* __restrict__ act,
                         const float* __restrict__ wq_o, const float* __restrict__ wq_a,
                         const float* __restrict__ cw,
                         const float* __restrict__ bias_o, const float* __restrict__ bias_a,
                         const float* __restrict__ cmask,
                         const float* __restrict__ omask, const float* __restrict__ amask,
                         short* __restrict__ S1, short* __restrict__ S2) {
  const int b = blockIdx.x;
  const int head = blockIdx.y;
  const short* Cb = (head ? Cw_a : Cw_o) + (size_t)b * KN * BH;
  const float* Qf = (head ? act : obs) + (size_t)b * LQ * BH;
  const float* wq = head ? wq_a : wq_o;
  const float* cwh = cw + head * BS * KN;
  const float* qmask = head ? amask : omask;
  const float bv = head ? bias_a[0] : bias_o[0];
  short* S1h = S1 + (size_t)head * BS * KN * LQ;
  short* S2h = S2 + (size_t)head * BS * KN * LQ;
  const int tid = threadIdx.x, lane = tid & 63, wave = tid >> 6;
  const int l15 = lane & 15, g4 = lane >> 4;
  const int m0 = (wave >> 1) * 16;      // c-rows of this wave
  const int qh = (wave & 1) * 128;      // q-half of this wave
  __shared__ __align__(16) short As[64 * 64];    // Cw tile (8 KB)
  __shared__ __align__(16) short Bs[256 * 64];   // Q tile (32 KB)
  __shared__ float qws[256];                      // inline-computed qw
  f32x4 acc[8] = {};
  float qacc[2] = {0.f, 0.f};
  const int brow = tid >> 2;        // 0..127
  const int s0 = (tid & 3) * 2;     // 16B slot pair

  for (int kk = 0; kk < BH; kk += 64) {
    {
      int row = tid >> 3, ls = tid & 7;
      bf16x8 v = *(const bf16x8*)(Cb + (size_t)row * BH + kk + ls * 8);
      *(bf16x8*)((char*)As + SWZ(row, row * 128 + ls * 16)) = v;
    }
#pragma unroll
    for (int it = 0; it < 2; ++it) {
      int row = it * 128 + brow;
#pragma unroll
      for (int u = 0; u < 2; ++u) {
        int d = kk + (s0 + u) * 8;
        const float* qp = Qf + (size_t)row * BH + d;
        f32x4 a = *(const f32x4*)qp;
        f32x4 c = *(const f32x4*)(qp + 4);
        f32x4 w0 = *(const f32x4*)(wq + d);
        f32x4 w1 = *(const f32x4*)(wq + d + 4);
        qacc[it] += a[0] * w0[0] + a[1] * w0[1] + a[2] * w0[2] + a[3] * w0[3] +
                    c[0] * w1[0] + c[1] * w1[1] + c[2] * w1[2] + c[3] * w1[3];
        bf16x8 v;
#pragma unroll
        for (int j = 0; j < 4; ++j) { v[j] = f2bf(a[j]); v[4 + j] = f2bf(c[j]); }
        *(bf16x8*)((char*)Bs + SWZ(row, row * 128 + (s0 + u) * 16)) = v;
      }
    }
    __syncthreads();
#pragma unroll
    for (int kb2 = 0; kb2 < 2; ++kb2) {
      int k16 = kb2 * 32 + g4 * 8;
      int arow = m0 + l15;
      bf16x8 af = *(const bf16x8*)((const char*)As + SWZ(arow, arow * 128 + k16 * 2));
#pragma unroll
      for (int f = 0; f < 8; ++f) {
        int nrow = qh + f * 16 + l15;
        bf16x8 bfr = *(const bf16x8*)((const char*)Bs + SWZ(nrow, nrow * 128 + k16 * 2));
        acc[f] = __builtin_amdgcn_mfma_f32_16x16x32_bf16(af, bfr, acc[f], 0, 0, 0);
      }
    }
    __syncthreads();
  }

  // finish inline qw: reduce across the 4 threads sharing a row
#pragma unroll
  for (int it = 0; it < 2; ++it) {
    qacc[it] += __shfl_xor(qacc[it], 1);
    qacc[it] += __shfl_xor(qacc[it], 2);
  }
  if ((tid & 3) == 0) { qws[brow] = qacc[0]; qws[128 + brow] = qacc[1]; }
  __syncthreads();

  float cmv[4], cwv[4], qmv[8], qwv[8];
#pragma unroll
  for (int e = 0; e < 4; ++e) {
    int c = m0 + g4 * 4 + e;
    cmv[e] = cmask[b * KN + c];
    cwv[e] = cwh[b * KN + c];
  }
#pragma unroll
  for (int f = 0; f < 8; ++f) {
    int q = qh + f * 16 + l15;
    qmv[f] = qmask[b * LQ + q];
    qwv[f] = qws[q] + bv;
  }
  float sraw[8][4];
#pragma unroll
  for (int f = 0; f < 8; ++f)
#pragma unroll
    for (int e = 0; e < 4; ++e) sraw[f][e] = acc[f][e] + cwv[e] + qwv[f];

  float* red = (float*)As;          // 8*128 floats (4 KB)
  float* red2 = (float*)As + 1024;  // 8*16
  float* red3 = (float*)As + 1152;  // 8*16

  // ---- c-softmax (per q, over 64 c), mask = cmask ----
  float wmax[8];
#pragma unroll
  for (int f = 0; f < 8; ++f) {
    float m = -1e30f;
#pragma unroll
    for (int e = 0; e < 4; ++e) m = fmaxf(m, clip15(sraw[f][e]) * cmv[e]);
    m = fmaxf(m, __shfl_xor(m, 16));
    m = fmaxf(m, __shfl_xor(m, 32));
    wmax[f] = m;
  }
  __syncthreads();  // done reading qws; As region reusable as red
  if (g4 == 0) {
#pragma unroll
    for (int f = 0; f < 8; ++f) red[wave * 128 + f * 16 + l15] = wmax[f];
  }
  __syncthreads();
  float cmax[8];
#pragma unroll
  for (int f = 0; f < 8; ++f) {
    int base = (wave & 1) * 128 + f * 16 + l15;
    float m = red[base];
#pragma unroll
    for (int w2 = 1; w2 < 4; ++w2) m = fmaxf(m, red[w2 * 256 + base]);
    cmax[f] = m;
  }
  __syncthreads();
  float wsum[8];
#pragma unroll
  for (int f = 0; f < 8; ++f) {
    float s = 0.f;
#pragma unroll
    for (int e = 0; e < 4; ++e) s += __expf(clip15(sraw[f][e]) * cmv[e] - cmax[f]) * cmv[e];
    s += __shfl_xor(s, 16);
    s += __shfl_xor(s, 32);
    wsum[f] = s;
  }
  if (g4 == 0) {
#pragma unroll
    for (int f = 0; f < 8; ++f) red[wave * 128 + f * 16 + l15] = wsum[f];
  }
  __syncthreads();
  float cinv[8];
#pragma unroll
  for (int f = 0; f < 8; ++f) {
    int base = (wave & 1) * 128 + f * 16 + l15;
    float s = 0.f;
#pragma unroll
    for (int w2 = 0; w2 < 4; ++w2) s += red[w2 * 256 + base];
    cinv[f] = 1.f / (s + 1e-6f);
  }
  __syncthreads();

  // ---- q-softmax (per c, over 256 q), mask = qmask ----
  float qmaxl[4];
#pragma unroll
  for (int e = 0; e < 4; ++e) {
    float m = -1e30f;
#pragma unroll
    for (int f = 0; f < 8; ++f) m = fmaxf(m, clip15(sraw[f][e]) * qmv[f]);
#pragma unroll
    for (int off = 8; off; off >>= 1) m = fmaxf(m, __shfl_xor(m, off));
    qmaxl[e] = m;
  }
  if (l15 == 0) {
#pragma unroll
    for (int e = 0; e < 4; ++e) red2[wave * 16 + g4 * 4 + e] = qmaxl[e];
  }
  __syncthreads();
  float qmax[4];
#pragma unroll
  for (int e = 0; e < 4; ++e)
    qmax[e] = fmaxf(red2[wave * 16 + g4 * 4 + e], red2[(wave ^ 1) * 16 + g4 * 4 + e]);
  float qsuml[4];
#pragma unroll
  for (int e = 0; e < 4; ++e) {
    float s = 0.f;
#pragma unroll
    for (int f = 0; f < 8; ++f) s += __expf(clip15(sraw[f][e]) * qmv[f] - qmax[e]) * qmv[f];
#pragma unroll
    for (int off = 8; off; off >>= 1) s += __shfl_xor(s, off);
    qsuml[e] = s;
  }
  if (l15 == 0) {
#pragma unroll
    for (int e = 0; e < 4; ++e) red3[wave * 16 + g4 * 4 + e] = qsuml[e];
  }
  __syncthreads();
  float qinv[4];
#pragma unroll
  for (int e = 0; e < 4; ++e)
    qinv[e] = 1.f / (red3[wave * 16 + g4 * 4 + e] + red3[(wave ^ 1) * 16 + g4 * 4 + e] + 1e-6f);

  // ---- writes ----
#pragma unroll
  for (int f = 0; f < 8; ++f) {
    int q = qh + f * 16 + l15;
#pragma unroll
    for (int e = 0; e < 4; ++e) {
      int c = m0 + g4 * 4 + e;
      size_t gi = ((size_t)b * KN + c) * LQ + q;
      float xq = clip15(sraw[f][e]) * qmv[f];
      float xc = clip15(sraw[f][e]) * cmv[e];
      S1h[gi] = f2bf(__expf(xq - qmax[e]) * qmv[f] * qinv[e]);
      S2h[gi] = f2bf(__expf(xc - cmax[f]) * cmv[e] * cinv[f]);
    }
  }
}

// ---------------- A/T/B GEMMs (both heads via blockIdx.z / .y) ----------------

__global__ void k_gemm_A_mfma(const short* __restrict__ S1,
                              const float* __restrict__ obs, const float* __restrict__ act,
                              const short* __restrict__ node_bf,
                              short* __restrict__ A_bf, short* __restrict__ CA_bf) {
  const int b = blockIdx.x, d0 = blockIdx.y * 64, head = blockIdx.z;
  const size_t hs = (size_t)head * BS * KN * LQ;
  const size_t hk = (size_t)head * BS * KN * BH;
  const int tid = threadIdx.x, lane = tid & 63, m0 = (tid >> 6) * 16;
  __shared__ __align__(16) short As[64 * 64];
  __shared__ __align__(16) short Bs[64 * 64];
  f32x4 acc[4] = {};
  const short* S1b = S1 + hs + (size_t)b * KN * LQ;
  const float* Qb = (head ? act : obs) + (size_t)b * LQ * BH;
  for (int kk = 0; kk < LQ; kk += 64) {
    stage_nat(S1b + kk, LQ, As, tid);
    stage_tr_f32(Qb + (size_t)kk * BH + d0, BH, Bs, tid);
    __syncthreads();
    mfma64(As, Bs, acc, lane, m0);
    __syncthreads();
  }
  const short* nb = node_bf + (size_t)b * KN * BH;
#pragma unroll
  for (int f = 0; f < 4; ++f) {
    int d = d0 + f * 16 + (lane & 15);
#pragma unroll
    for (int e = 0; e < 4; ++e) {
      int c = m0 + (lane >> 4) * 4 + e;
      size_t gi = ((size_t)b * KN + c) * BH + d;
      float av = acc[f][e];
      A_bf[hk + gi] = f2bf(av);
      CA_bf[hk + gi] = f2bf(bf2f(nb[(size_t)c * BH + d]) * av);
    }
  }
}

__global__ void k_gemm_T_mfma(const short* __restrict__ S1, const short* __restrict__ S2,
                              short* __restrict__ T) {
  const int b = blockIdx.x, head = blockIdx.y;
  const size_t hs = (size_t)head * BS * KN * LQ;
  const int tid = threadIdx.x, lane = tid & 63, m0 = (tid >> 6) * 16;
  __shared__ __align__(16) short As[64 * 64];
  __shared__ __align__(16) short Bs[64 * 64];
  f32x4 acc[4] = {};
  const short* S1b = S1 + hs + (size_t)b * KN * LQ;
  const short* S2b = S2 + hs + (size_t)b * KN * LQ;
  for (int kk = 0; kk < LQ; kk += 64) {
    stage_nat(S1b + kk, LQ, As, tid);
    stage_nat(S2b + kk, LQ, Bs, tid);
    __syncthreads();
    mfma64(As, Bs, acc, lane, m0);
    __syncthreads();
  }
  short* Th = T + (size_t)head * BS * KN * KN;
#pragma unroll
  for (int f = 0; f < 4; ++f) {
    int k2 = f * 16 + (lane & 15);
#pragma unroll
    for (int e = 0; e < 4; ++e) {
      int c = m0 + (lane >> 4) * 4 + e;
      Th[((size_t)b * KN + c) * KN + k2] = f2bf(acc[f][e]);
    }
  }
}

__global__ void k_gemm_B_mfma(const short* __restrict__ T, const short* __restrict__ node_bf,
                              short* __restrict__ CB_bf) {
  const int b = blockIdx.x, d0 = blockIdx.y * 64, head = blockIdx.z;
  const int tid = threadIdx.x, lane = tid & 63, m0 = (tid >> 6) * 16;
  __shared__ __align__(16) short As[64 * 64];
  __shared__ __align__(16) short Bs[64 * 64];
  f32x4 acc[4] = {};
  const short* nb = node_bf + (size_t)b * KN * BH;
  stage_nat(T + (size_t)head * BS * KN * KN + (size_t)b * KN * KN, KN, As, tid);
  stage_tr(nb + d0, BH, Bs, tid);
  __syncthreads();
  mfma64(As, Bs, acc, lane, m0);
  short* CBh = CB_bf + (size_t)head * BS * KN * BH;
#pragma unroll
  for (int f = 0; f < 4; ++f) {
    int d = d0 + f * 16 + (lane & 15);
#pragma unroll
    for (int e = 0; e < 4; ++e) {
      int c = m0 + (lane >> 4) * 4 + e;
      CBh[((size_t)b * KN + c) * BH + d] = f2bf(bf2f(nb[(size_t)c * BH + d]) * acc[f][e]);
    }
  }
}

// ---------------- proj: feat[32768 x 2048] @ prjT -> H ----------------
// 256row x 128o tile, 512 threads, K=2048. T3-min 2-phase: double-buffer,
// STAGE(t+1) issued BEFORE COMPUTE(t), ONE barrier + vmcnt(0) per step.
__global__ void k_proj_big(const short* __restrict__ node_bf, const short* __restrict__ A_bf,
                           const short* __restrict__ CA_bf, const short* __restrict__ CB_bf,
                           const short* __restrict__ prjT,
                           short* __restrict__ Hno, short* __restrict__ Hna) {
  const int l = blockIdx.x;            // 512
  const int xcd = l & 7;
  const int u = l >> 3;                // 0..63
  const int head = u & 1;
  const int o0 = ((u >> 1) & 3) * 128;
  const int mt = xcd * 8 + (u >> 3);   // 0..63
  const int r0 = mt * 256;
  const size_t hk = (size_t)head * BS * KN * BH;
  const int tid = threadIdx.x, lane = tid & 63, wave = tid >> 6;  // 8 waves
  const int l15 = lane & 15, g4 = lane >> 4;
  const int m0 = wave * 32;
  __shared__ __align__(16) short As[2][256 * 64];   // 2 x 32 KB
  __shared__ __align__(16) short Bs[2][128 * 64];   // 2 x 16 KB
  f32x4 acc[16] = {};
  const short* segs[4] = {node_bf, A_bf + hk, CA_bf + hk, CB_bf + hk};
  const short* Bpanel = prjT + (size_t)head * BH * 2048 + (size_t)o0 * 2048;
  const int lr = lane >> 3;   // row within 8-row call
  const int ls = lane & 7;    // 16B slot within row

  auto STAGE = [&](int t, int buf) {
    const int kk = t * 64;
    const short* Aseg = segs[kk >> 9] + (size_t)r0 * BH + (kk & 511);
#pragma unroll
    for (int c = 0; c < 4; ++c) {
      int row = wave * 32 + c * 8 + lr;
      int sw = ls ^ ((row ^ (row >> 3)) & 7);
      gl_lds16(Aseg + (size_t)row * BH + sw * 8, As[buf] + (wave * 32 + c * 8) * 64);
    }
#pragma unroll
    for (int c = 0; c < 2; ++c) {
      int row = wave * 16 + c * 8 + lr;
      int sw = ls ^ ((row ^ (row >> 3)) & 7);
      gl_lds16(Bpanel + (size_t)row * 2048 + kk + sw * 8, Bs[buf] + (wave * 16 + c * 8) * 64);
    }
  };
  auto COMPUTE = [&](int buf) {
    const short* Ac = As[buf];
    const short* Bc = Bs[buf];
#pragma unroll
    for (int kb2 = 0; kb2 < 2; ++kb2) {
      int k16 = kb2 * 32 + g4 * 8;
#pragma unroll
      for (int mi = 0; mi < 2; ++mi) {
        int arow = m0 + mi * 16 + l15;
        bf16x8 af = *(const bf16x8*)((const char*)Ac + SWZ(arow, arow * 128 + k16 * 2));
#pragma unroll
        for (int f = 0; f < 8; ++f) {
          int nrow = f * 16 + l15;
          bf16x8 bfr = *(const bf16x8*)((const char*)Bc + SWZ(nrow, nrow * 128 + k16 * 2));
          acc[mi * 8 + f] = __builtin_amdgcn_mfma_f32_16x16x32_bf16(af, bfr, acc[mi * 8 + f], 0, 0, 0);
        }
      }
    }
  };

  STAGE(0, 0);
  asm volatile("s_waitcnt vmcnt(0)" ::: "memory");
  __builtin_amdgcn_s_barrier();
  int cur = 0;
  for (int t = 0; t < 31; ++t) {
    STAGE(t + 1, cur ^ 1);   // in flight during COMPUTE below
    COMPUTE(cur);
    asm volatile("s_waitcnt vmcnt(0)" ::: "memory");
    __builtin_amdgcn_s_barrier();
    cur ^= 1;
  }
  COMPUTE(cur);  // t = 31

  short* H = head ? Hna : Hno;
#pragma unroll
  for (int mi = 0; mi < 2; ++mi) {
#pragma unroll
    for (int f = 0; f < 8; ++f) {
      int o = o0 + f * 16 + l15;
#pragma unroll
      for (int e = 0; e < 4; ++e) {
        int row = r0 + m0 + mi * 16 + g4 * 4 + e;
        H[(size_t)row * BH + o] = f2bf(acc[mi * 8 + f][e]);
      }
    }
  }
}

// Grouped GEMM, full K=1536. T3-min 2-phase double-buffer (one barrier/step).
__global__ void k_blk_mfma(const short* __restrict__ Hno, const short* __restrict__ Hna,
                           const short* __restrict__ node_bf, const float* __restrict__ rew,
                           const short* __restrict__ WT, const float* __restrict__ W,
                           const float* __restrict__ bias, float* __restrict__ out) {
  const int l = blockIdx.x;            // 1024
  const int xcd = l & 7;
  const int idx = l >> 3;              // 0..127
  const int kb = xcd * 8 + (idx & 7);
  const int tile = idx >> 3;           // 0..15
  const int b0 = (tile & 3) * 64, o0 = (tile >> 2) * 128;
  const int tid = threadIdx.x, lane = tid & 63, wave = tid >> 6;
  const int l15 = lane & 15, g4 = lane >> 4;
  const int m0 = wave * 16;
  __shared__ __align__(16) short As[2][64 * 64];    // 2 x 8 KB
  __shared__ __align__(16) short Bs[2][128 * 64];   // 2 x 16 KB
  f32x4 acc[8] = {};
  const short* segs[3] = {Hno, Hna, node_bf};
  const short* Bpanel = WT + ((size_t)kb * BH + o0) * 1536;
  const int lr = lane >> 3;
  const int ls = lane & 7;

  auto STAGE = [&](int t, int buf) {
    const int kk = t * 64;
    const short* Aseg = segs[kk >> 9] + (size_t)kb * BH + (kk & 511);
#pragma unroll
    for (int c = 0; c < 2; ++c) {
      int row = wave * 16 + c * 8 + lr;
      int sw = ls ^ ((row ^ (row >> 3)) & 7);
      gl_lds16(Aseg + ((size_t)(b0 + row) * KN) * BH + sw * 8,
               As[buf] + (wave * 16 + c * 8) * 64);
    }
#pragma unroll
    for (int c = 0; c < 4; ++c) {
      int row = wave * 32 + c * 8 + lr;
      int sw = ls ^ ((row ^ (row >> 3)) & 7);
      gl_lds16(Bpanel + (size_t)row * 1536 + kk + sw * 8,
               Bs[buf] + (wave * 32 + c * 8) * 64);
    }
  };
  auto COMPUTE = [&](int buf) {
    const short* Ac = As[buf];
    const short* Bc = Bs[buf];
#pragma unroll
    for (int kb2 = 0; kb2 < 2; ++kb2) {
      int k16 = kb2 * 32 + g4 * 8;
      int arow = m0 + l15;
      bf16x8 af = *(const bf16x8*)((const char*)Ac + SWZ(arow, arow * 128 + k16 * 2));
#pragma unroll
      for (int f = 0; f < 8; ++f) {
        int nrow = f * 16 + l15;
        bf16x8 bfr = *(const bf16x8*)((const char*)Bc + SWZ(nrow, nrow * 128 + k16 * 2));
        acc[f] = __builtin_amdgcn_mfma_f32_16x16x32_bf16(af, bfr, acc[f], 0, 0, 0);
      }
    }
  };

  STAGE(0, 0);
  asm volatile("s_waitcnt vmcnt(0)" ::: "memory");
  __builtin_amdgcn_s_barrier();
  int cur = 0;
  for (int t = 0; t < 23; ++t) {
    STAGE(t + 1, cur ^ 1);
    COMPUTE(cur);
    asm volatile("s_waitcnt vmcnt(0)" ::: "memory");
    __builtin_amdgcn_s_barrier();
    cur ^= 1;
  }
  COMPUTE(cur);  // t = 23

  const float* Wrow = W + (size_t)kb * SUB_IN * BH + (size_t)1536 * BH;
  const float* bkb = bias + kb * BH;
#pragma unroll
  for (int f = 0; f < 8; ++f) {
    int o = o0 + f * 16 + l15;
    float wr = Wrow[o];
    float bv = bkb[o];
#pragma unroll
    for (int e = 0; e < 4; ++e) {
      int bb = b0 + m0 + g4 * 4 + e;
      out[((size_t)bb * KN + kb) * BH + o] = acc[f][e] + rew[bb] * wr + bv;
    }
  }
}

extern "C" void kernel_launch(void* const* d_in, const int* in_sizes, int n_in,
                              void* d_out, int out_size, void* d_ws, size_t ws_size,
                              hipStream_t stream) {
  (void)in_sizes; (void)n_in; (void)out_size; (void)ws_size;
  const float* act   = (const float*)d_in[0];
  const float* obs   = (const float*)d_in[1];
  const float* amask = (const float*)d_in[2];
  const float* omask = (const float*)d_in[3];
  const float* rew   = (const float*)d_in[4];
  const float* node  = (const float*)d_in[5];
  const float* nmask = (const float*)d_in[6];
  const float* w4C_o = (const float*)d_in[7];
  const float* w4Q_o = (const float*)d_in[8];
  const float* w4m_o = (const float*)d_in[9];
  const float* bias_o= (const float*)d_in[10];
  const float* w4C_a = (const float*)d_in[11];
  const float* w4Q_a = (const float*)d_in[12];
  const float* w4m_a = (const float*)d_in[13];
  const float* bias_a= (const float*)d_in[14];
  const float* prj_o = (const float*)d_in[15];
  const float* prj_a = (const float*)d_in[16];
  const float* blkW  = (const float*)d_in[17];
  const float* blkb  = (const float*)d_in[18];
  float* out = (float*)d_out;

  char* wsb = (char*)d_ws;
  auto alloc = [&](size_t bytes) { char* p = wsb; wsb += (bytes + 255) & ~255ull; return p; };
  const size_t NKB = (size_t)BS * KN * BH;   // 8.4M elems
  const size_t NS  = (size_t)BS * KN * LQ;   // 4.2M elems
  short* node_bf = (short*)alloc(NKB * 2);
  short* Cw_o    = (short*)alloc(NKB * 2);
  short* Cw_a    = (short*)alloc(NKB * 2);
  short* prjT    = (short*)alloc((size_t)2 * BH * 2048 * 2);
  short* S1      = (short*)alloc((size_t)2 * NS * 2);
  short* S2      = (short*)alloc((size_t)2 * NS * 2);
  short* A_bf    = (short*)alloc((size_t)2 * NKB * 2);
  short* CA_bf   = (short*)alloc((size_t)2 * NKB * 2);
  short* CB_bf   = (short*)alloc((size_t)2 * NKB * 2);
  short* T_bf    = (short*)alloc((size_t)2 * BS * KN * KN * 2);
  short* Hno     = (short*)alloc(NKB * 2);
  short* Hna     = (short*)alloc(NKB * 2);
  short* WT      = (short*)alloc((size_t)KN * BH * 1536 * 2);
  float* cw      = (float*)alloc((size_t)2 * BS * KN * 4);

  k_cvtC2<<<dim3(BS * KN / 4), 256, 0, stream>>>(node, w4C_o, w4C_a, w4m_o, w4m_a,
                                                 node_bf, Cw_o, Cw_a, cw, cw + BS * KN);
  k_prjT<<<dim3(64, 16, 2), 256, 0, stream>>>(prj_o, prj_a, prjT);
  k_WT<<<dim3(48, 16, 64), 256, 0, stream>>>(blkW, WT);
  k_score2<<<dim3(BS, 2), 512, 0, stream>>>(Cw_o, Cw_a, obs, act, w4Q_o, w4Q_a, cw,
                                            bias_o, bias_a, nmask, omask, amask, S1, S2);
  k_gemm_A_mfma<<<dim3(BS, BH / 64, 2), 256, 0, stream>>>(S1, obs, act, node_bf, A_bf, CA_bf);
  k_gemm_T_mfma<<<dim3(BS, 2), 256, 0, stream>>>(S1, S2, T_bf);
  k_gemm_B_mfma<<<dim3(BS, BH / 64, 2), 256, 0, stream>>>(T_bf, node_bf, CB_bf);
  k_proj_big<<<dim3(512), 512, 0, stream>>>(node_bf, A_bf, CA_bf, CB_bf, prjT, Hno, Hna);
  k_blk_mfma<<<dim3(1024), 256, 0, stream>>>(Hno, Hna, node_bf, rew, WT, blkW, blkb, out);
}

// Round 13
// 499.130 us; speedup vs baseline: 1.1955x; 1.1955x over previous
//
#include <hip/hip_runtime.h>
#include <math.h>

#define BS 256
#define LQ 256
#define KN 64
#define BH 512
#define SUB_IN 1537

typedef __attribute__((ext_vector_type(8))) short bf16x8;
typedef __attribute__((ext_vector_type(4))) float f32x4;

__device__ __forceinline__ float clip15(float x) {
  return fminf(fmaxf(x, -15.f), 15.f);
}
__device__ __forceinline__ short f2bf(float f) {
  unsigned u = __float_as_uint(f);
  u = u + 0x7fffu + ((u >> 16) & 1u);
  return (short)(u >> 16);
}
__device__ __forceinline__ float bf2f(short s) {
  return __uint_as_float(((unsigned)(unsigned short)s) << 16);
}

// XOR swizzle on the 16B slot within each 128B LDS row (proven R2-R12)
#define SWZ(row, byte) ((byte) ^ (((((row) ^ ((row) >> 3)) & 7)) << 4))

// async global->LDS, 16B per lane; LDS dest = wave-uniform base + lane*16
__device__ __forceinline__ void gl_lds16(const short* g, short* l) {
  __builtin_amdgcn_global_load_lds(
      (const __attribute__((address_space(1))) void*)g,
      (__attribute__((address_space(3))) void*)l, 16, 0, 0);
}

// ---------------- prep kernels ----------------

// one pass over node: node_bf, Cw_o = node*wm_o, Cw_a = node*wm_a, cw_o/cw_a rowdots
__global__ void k_cvtC2(const float* __restrict__ X,
                        const float* __restrict__ wc_o, const float* __restrict__ wc_a,
                        const float* __restrict__ wm_o, const float* __restrict__ wm_a,
                        short* __restrict__ Xbf, short* __restrict__ Xw_o,
                        short* __restrict__ Xw_a,
                        float* __restrict__ rd_o, float* __restrict__ rd_a) {
  int row = blockIdx.x * 4 + (threadIdx.x >> 6);
  int lane = threadIdx.x & 63;
  const float* x = X + (size_t)row * BH + lane * 8;
  f32x4 v0 = *(const f32x4*)x;
  f32x4 v1 = *(const f32x4*)(x + 4);
  f32x4 co0 = *(const f32x4*)(wc_o + lane * 8);
  f32x4 co1 = *(const f32x4*)(wc_o + lane * 8 + 4);
  f32x4 ca0 = *(const f32x4*)(wc_a + lane * 8);
  f32x4 ca1 = *(const f32x4*)(wc_a + lane * 8 + 4);
  float so = v0[0] * co0[0] + v0[1] * co0[1] + v0[2] * co0[2] + v0[3] * co0[3] +
             v1[0] * co1[0] + v1[1] * co1[1] + v1[2] * co1[2] + v1[3] * co1[3];
  float sa = v0[0] * ca0[0] + v0[1] * ca0[1] + v0[2] * ca0[2] + v0[3] * ca0[3] +
             v1[0] * ca1[0] + v1[1] * ca1[1] + v1[2] * ca1[2] + v1[3] * ca1[3];
#pragma unroll
  for (int off = 32; off; off >>= 1) { so += __shfl_down(so, off); sa += __shfl_down(sa, off); }
  if (lane == 0) { rd_o[row] = so; rd_a[row] = sa; }
  f32x4 mo0 = *(const f32x4*)(wm_o + lane * 8);
  f32x4 mo1 = *(const f32x4*)(wm_o + lane * 8 + 4);
  f32x4 ma0 = *(const f32x4*)(wm_a + lane * 8);
  f32x4 ma1 = *(const f32x4*)(wm_a + lane * 8 + 4);
  bf16x8 ob, oo, oa;
#pragma unroll
  for (int j = 0; j < 4; ++j) {
    ob[j] = f2bf(v0[j]);          ob[4 + j] = f2bf(v1[j]);
    oo[j] = f2bf(v0[j] * mo0[j]); oo[4 + j] = f2bf(v1[j] * mo1[j]);
    oa[j] = f2bf(v0[j] * ma0[j]); oa[4 + j] = f2bf(v1[j] * ma1[j]);
  }
  size_t gi = (size_t)row * BH + lane * 8;
  *(bf16x8*)(Xbf + gi) = ob;
  *(bf16x8*)(Xw_o + gi) = oo;
  *(bf16x8*)(Xw_a + gi) = oa;
}

// prjT[head][n][k] = bf16(prj_head[k][n]); k=2048, n=512
__global__ void k_prjT(const float* __restrict__ prj_o, const float* __restrict__ prj_a,
                       short* __restrict__ prjT) {
  __shared__ float t[32][33];
  int k0 = blockIdx.x * 32, n0 = blockIdx.y * 32, head = blockIdx.z;
  const float* prj = head ? prj_a : prj_o;
  short* dst = prjT + (size_t)head * BH * 2048;
  int x = threadIdx.x & 31, y = threadIdx.x >> 5;  // 32x8
  for (int yy = y; yy < 32; yy += 8)
    t[yy][x] = prj[(size_t)(k0 + yy) * BH + n0 + x];
  __syncthreads();
  for (int yy = y; yy < 32; yy += 8)
    dst[(size_t)(n0 + yy) * 2048 + k0 + x] = f2bf(t[x][yy]);
}

// WT[kb][o][s] = bf16(W[kb][s][o]); s<1536 only
__global__ void k_WT(const float* __restrict__ W, short* __restrict__ WT) {
  __shared__ float t[32][33];
  int s0 = blockIdx.x * 32, o0 = blockIdx.y * 32, kb = blockIdx.z;
  const float* Wk = W + (size_t)kb * SUB_IN * BH;
  int x = threadIdx.x & 31, y = threadIdx.x >> 5;
  for (int yy = y; yy < 32; yy += 8)
    t[yy][x] = Wk[(size_t)(s0 + yy) * BH + o0 + x];
  __syncthreads();
  for (int yy = y; yy < 32; yy += 8)
    WT[((size_t)kb * BH + o0 + yy) * 1536 + s0 + x] = f2bf(t[x][yy]);
}

// ---------------- staging helpers ----------------

__device__ __forceinline__ void stage_nat(const short* __restrict__ src, size_t ld,
                                          short* As, int tid) {
  int kl = (tid & 15) * 4;
#pragma unroll
  for (int it = 0; it < 4; ++it) {
    int row = (tid >> 4) + it * 16;
    short4 v = *(const short4*)(src + (size_t)row * ld + kl);
    *(short4*)((char*)As + SWZ(row, row * 128 + kl * 2)) = v;
  }
}

__device__ __forceinline__ void stage_tr(const short* __restrict__ src, size_t ld,
                                         short* Bs, int tid) {
  int n0 = (tid & 15) * 4;
  int k0 = (tid >> 4) * 4;
  short4 r0 = *(const short4*)(src + (size_t)(k0 + 0) * ld + n0);
  short4 r1 = *(const short4*)(src + (size_t)(k0 + 1) * ld + n0);
  short4 r2 = *(const short4*)(src + (size_t)(k0 + 2) * ld + n0);
  short4 r3 = *(const short4*)(src + (size_t)(k0 + 3) * ld + n0);
  *(short4*)((char*)Bs + SWZ(n0 + 0, (n0 + 0) * 128 + k0 * 2)) = make_short4(r0.x, r1.x, r2.x, r3.x);
  *(short4*)((char*)Bs + SWZ(n0 + 1, (n0 + 1) * 128 + k0 * 2)) = make_short4(r0.y, r1.y, r2.y, r3.y);
  *(short4*)((char*)Bs + SWZ(n0 + 2, (n0 + 2) * 128 + k0 * 2)) = make_short4(r0.z, r1.z, r2.z, r3.z);
  *(short4*)((char*)Bs + SWZ(n0 + 3, (n0 + 3) * 128 + k0 * 2)) = make_short4(r0.w, r1.w, r2.w, r3.w);
}

// transposed: f32 source [k][n] (stride ld) -> Bs[n][k] with convert (proven R2)
__device__ __forceinline__ void stage_tr_f32(const float* __restrict__ src, size_t ld,
                                             short* Bs, int tid) {
  int n0 = (tid & 15) * 4;
  int k0 = (tid >> 4) * 4;
  f32x4 r0 = *(const f32x4*)(src + (size_t)(k0 + 0) * ld + n0);
  f32x4 r1 = *(const f32x4*)(src + (size_t)(k0 + 1) * ld + n0);
  f32x4 r2 = *(const f32x4*)(src + (size_t)(k0 + 2) * ld + n0);
  f32x4 r3 = *(const f32x4*)(src + (size_t)(k0 + 3) * ld + n0);
#pragma unroll
  for (int j = 0; j < 4; ++j) {
    int n = n0 + j;
    *(short4*)((char*)Bs + SWZ(n, n * 128 + k0 * 2)) =
        make_short4(f2bf(r0[j]), f2bf(r1[j]), f2bf(r2[j]), f2bf(r3[j]));
  }
}

__device__ __forceinline__ void mfma64(const short* As, const short* Bs,
                                       f32x4 acc[4], int lane, int m0) {
#pragma unroll
  for (int kb = 0; kb < 2; ++kb) {
    int k16 = kb * 32 + (lane >> 4) * 8;
    int arow = m0 + (lane & 15);
    bf16x8 af = *(const bf16x8*)((const char*)As + SWZ(arow, arow * 128 + k16 * 2));
#pragma unroll
    for (int f = 0; f < 4; ++f) {
      int nrow = f * 16 + (lane & 15);
      bf16x8 bfr = *(const bf16x8*)((const char*)Bs + SWZ(nrow, nrow * 128 + k16 * 2));
      acc[f] = __builtin_amdgcn_mfma_f32_16x16x32_bf16(af, bfr, acc[f], 0, 0, 0);
    }
  }
}

// ---------------- fused score + dual softmax + inline qw rowdot ----------------
__global__ void k_score2(const short* __restrict__ Cw_o, const short* __restrict__ Cw_a,
                         const float* __restrict__ obs, const float* __restrict__ act,
                         const float* __restrict__ wq_o, const float* __restrict__ wq_a,
                         const float* __restrict__ cw,
                         const float* __restrict__ bias_o, const float* __restrict__ bias_a,
                         const float* __restrict__ cmask,
                         const float* __restrict__ omask, const float* __restrict__ amask,
                         short* __restrict__ S1, short* __restrict__ S2) {
  const int b = blockIdx.x;
  const int head = blockIdx.y;
  const short* Cb = (head ? Cw_a : Cw_o) + (size_t)b * KN * BH;
  const float* Qf = (head ? act : obs) + (size_t)b * LQ * BH;
  const float* wq = head ? wq_a : wq_o;
  const float* cwh = cw + head * BS * KN;
  const float* qmask = head ? amask : omask;
  const float bv = head ? bias_a[0] : bias_o[0];
  short* S1h = S1 + (size_t)head * BS * KN * LQ;
  short* S2h = S2 + (size_t)head * BS * KN * LQ;
  const int tid = threadIdx.x, lane = tid & 63, wave = tid >> 6;
  const int l15 = lane & 15, g4 = lane >> 4;
  const int m0 = (wave >> 1) * 16;      // c-rows of this wave
  const int qh = (wave & 1) * 128;      // q-half of this wave
  __shared__ __align__(16) short As[64 * 64];    // Cw tile (8 KB)
  __shared__ __align__(16) short Bs[256 * 64];   // Q tile (32 KB)
  __shared__ float qws[256];                      // inline-computed qw
  f32x4 acc[8] = {};
  float qacc[2] = {0.f, 0.f};
  const int brow = tid >> 2;        // 0..127
  const int s0 = (tid & 3) * 2;     // 16B slot pair

  for (int kk = 0; kk < BH; kk += 64) {
    {
      int row = tid >> 3, ls = tid & 7;
      bf16x8 v = *(const bf16x8*)(Cb + (size_t)row * BH + kk + ls * 8);
      *(bf16x8*)((char*)As + SWZ(row, row * 128 + ls * 16)) = v;
    }
#pragma unroll
    for (int it = 0; it < 2; ++it) {
      int row = it * 128 + brow;
#pragma unroll
      for (int u = 0; u < 2; ++u) {
        int d = kk + (s0 + u) * 8;
        const float* qp = Qf + (size_t)row * BH + d;
        f32x4 a = *(const f32x4*)qp;
        f32x4 c = *(const f32x4*)(qp + 4);
        f32x4 w0 = *(const f32x4*)(wq + d);
        f32x4 w1 = *(const f32x4*)(wq + d + 4);
        qacc[it] += a[0] * w0[0] + a[1] * w0[1] + a[2] * w0[2] + a[3] * w0[3] +
                    c[0] * w1[0] + c[1] * w1[1] + c[2] * w1[2] + c[3] * w1[3];
        bf16x8 v;
#pragma unroll
        for (int j = 0; j < 4; ++j) { v[j] = f2bf(a[j]); v[4 + j] = f2bf(c[j]); }
        *(bf16x8*)((char*)Bs + SWZ(row, row * 128 + (s0 + u) * 16)) = v;
      }
    }
    __syncthreads();
#pragma unroll
    for (int kb2 = 0; kb2 < 2; ++kb2) {
      int k16 = kb2 * 32 + g4 * 8;
      int arow = m0 + l15;
      bf16x8 af = *(const bf16x8*)((const char*)As + SWZ(arow, arow * 128 + k16 * 2));
#pragma unroll
      for (int f = 0; f < 8; ++f) {
        int nrow = qh + f * 16 + l15;
        bf16x8 bfr = *(const bf16x8*)((const char*)Bs + SWZ(nrow, nrow * 128 + k16 * 2));
        acc[f] = __builtin_amdgcn_mfma_f32_16x16x32_bf16(af, bfr, acc[f], 0, 0, 0);
      }
    }
    __syncthreads();
  }

  // finish inline qw: reduce across the 4 threads sharing a row
#pragma unroll
  for (int it = 0; it < 2; ++it) {
    qacc[it] += __shfl_xor(qacc[it], 1);
    qacc[it] += __shfl_xor(qacc[it], 2);
  }
  if ((tid & 3) == 0) { qws[brow] = qacc[0]; qws[128 + brow] = qacc[1]; }
  __syncthreads();

  float cmv[4], cwv[4], qmv[8], qwv[8];
#pragma unroll
  for (int e = 0; e < 4; ++e) {
    int c = m0 + g4 * 4 + e;
    cmv[e] = cmask[b * KN + c];
    cwv[e] = cwh[b * KN + c];
  }
#pragma unroll
  for (int f = 0; f < 8; ++f) {
    int q = qh + f * 16 + l15;
    qmv[f] = qmask[b * LQ + q];
    qwv[f] = qws[q] + bv;
  }
  float sraw[8][4];
#pragma unroll
  for (int f = 0; f < 8; ++f)
#pragma unroll
    for (int e = 0; e < 4; ++e) sraw[f][e] = acc[f][e] + cwv[e] + qwv[f];

  float* red = (float*)As;          // 8*128 floats (4 KB)
  float* red2 = (float*)As + 1024;  // 8*16
  float* red3 = (float*)As + 1152;  // 8*16

  // ---- c-softmax (per q, over 64 c), mask = cmask ----
  float wmax[8];
#pragma unroll
  for (int f = 0; f < 8; ++f) {
    float m = -1e30f;
#pragma unroll
    for (int e = 0; e < 4; ++e) m = fmaxf(m, clip15(sraw[f][e]) * cmv[e]);
    m = fmaxf(m, __shfl_xor(m, 16));
    m = fmaxf(m, __shfl_xor(m, 32));
    wmax[f] = m;
  }
  __syncthreads();  // done reading qws; As region reusable as red
  if (g4 == 0) {
#pragma unroll
    for (int f = 0; f < 8; ++f) red[wave * 128 + f * 16 + l15] = wmax[f];
  }
  __syncthreads();
  float cmax[8];
#pragma unroll
  for (int f = 0; f < 8; ++f) {
    int base = (wave & 1) * 128 + f * 16 + l15;
    float m = red[base];
#pragma unroll
    for (int w2 = 1; w2 < 4; ++w2) m = fmaxf(m, red[w2 * 256 + base]);
    cmax[f] = m;
  }
  __syncthreads();
  float wsum[8];
#pragma unroll
  for (int f = 0; f < 8; ++f) {
    float s = 0.f;
#pragma unroll
    for (int e = 0; e < 4; ++e) s += __expf(clip15(sraw[f][e]) * cmv[e] - cmax[f]) * cmv[e];
    s += __shfl_xor(s, 16);
    s += __shfl_xor(s, 32);
    wsum[f] = s;
  }
  if (g4 == 0) {
#pragma unroll
    for (int f = 0; f < 8; ++f) red[wave * 128 + f * 16 + l15] = wsum[f];
  }
  __syncthreads();
  float cinv[8];
#pragma unroll
  for (int f = 0; f < 8; ++f) {
    int base = (wave & 1) * 128 + f * 16 + l15;
    float s = 0.f;
#pragma unroll
    for (int w2 = 0; w2 < 4; ++w2) s += red[w2 * 256 + base];
    cinv[f] = 1.f / (s + 1e-6f);
  }
  __syncthreads();

  // ---- q-softmax (per c, over 256 q), mask = qmask ----
  float qmaxl[4];
#pragma unroll
  for (int e = 0; e < 4; ++e) {
    float m = -1e30f;
#pragma unroll
    for (int f = 0; f < 8; ++f) m = fmaxf(m, clip15(sraw[f][e]) * qmv[f]);
#pragma unroll
    for (int off = 8; off; off >>= 1) m = fmaxf(m, __shfl_xor(m, off));
    qmaxl[e] = m;
  }
  if (l15 == 0) {
#pragma unroll
    for (int e = 0; e < 4; ++e) red2[wave * 16 + g4 * 4 + e] = qmaxl[e];
  }
  __syncthreads();
  float qmax[4];
#pragma unroll
  for (int e = 0; e < 4; ++e)
    qmax[e] = fmaxf(red2[wave * 16 + g4 * 4 + e], red2[(wave ^ 1) * 16 + g4 * 4 + e]);
  float qsuml[4];
#pragma unroll
  for (int e = 0; e < 4; ++e) {
    float s = 0.f;
#pragma unroll
    for (int f = 0; f < 8; ++f) s += __expf(clip15(sraw[f][e]) * qmv[f] - qmax[e]) * qmv[f];
#pragma unroll
    for (int off = 8; off; off >>= 1) s += __shfl_xor(s, off);
    qsuml[e] = s;
  }
  if (l15 == 0) {
#pragma unroll
    for (int e = 0; e < 4; ++e) red3[wave * 16 + g4 * 4 + e] = qsuml[e];
  }
  __syncthreads();
  float qinv[4];
#pragma unroll
  for (int e = 0; e < 4; ++e)
    qinv[e] = 1.f / (red3[wave * 16 + g4 * 4 + e] + red3[(wave ^ 1) * 16 + g4 * 4 + e] + 1e-6f);

  // ---- writes ----
#pragma unroll
  for (int f = 0; f < 8; ++f) {
    int q = qh + f * 16 + l15;
#pragma unroll
    for (int e = 0; e < 4; ++e) {
      int c = m0 + g4 * 4 + e;
      size_t gi = ((size_t)b * KN + c) * LQ + q;
      float xq = clip15(sraw[f][e]) * qmv[f];
      float xc = clip15(sraw[f][e]) * cmv[e];
      S1h[gi] = f2bf(__expf(xq - qmax[e]) * qmv[f] * qinv[e]);
      S2h[gi] = f2bf(__expf(xc - cmax[f]) * cmv[e] * cinv[f]);
    }
  }
}

// ---------------- A GEMM (both heads via blockIdx.z) ----------------

__global__ void k_gemm_A_mfma(const short* __restrict__ S1,
                              const float* __restrict__ obs, const float* __restrict__ act,
                              const short* __restrict__ node_bf,
                              short* __restrict__ A_bf, short* __restrict__ CA_bf) {
  const int b = blockIdx.x, d0 = blockIdx.y * 64, head = blockIdx.z;
  const size_t hs = (size_t)head * BS * KN * LQ;
  const size_t hk = (size_t)head * BS * KN * BH;
  const int tid = threadIdx.x, lane = tid & 63, m0 = (tid >> 6) * 16;
  __shared__ __align__(16) short As[64 * 64];
  __shared__ __align__(16) short Bs[64 * 64];
  f32x4 acc[4] = {};
  const short* S1b = S1 + hs + (size_t)b * KN * LQ;
  const float* Qb = (head ? act : obs) + (size_t)b * LQ * BH;
  for (int kk = 0; kk < LQ; kk += 64) {
    stage_nat(S1b + kk, LQ, As, tid);
    stage_tr_f32(Qb + (size_t)kk * BH + d0, BH, Bs, tid);
    __syncthreads();
    mfma64(As, Bs, acc, lane, m0);
    __syncthreads();
  }
  const short* nb = node_bf + (size_t)b * KN * BH;
#pragma unroll
  for (int f = 0; f < 4; ++f) {
    int d = d0 + f * 16 + (lane & 15);
#pragma unroll
    for (int e = 0; e < 4; ++e) {
      int c = m0 + (lane >> 4) * 4 + e;
      size_t gi = ((size_t)b * KN + c) * BH + d;
      float av = acc[f][e];
      A_bf[hk + gi] = f2bf(av);
      CA_bf[hk + gi] = f2bf(bf2f(nb[(size_t)c * BH + d]) * av);
    }
  }
}

// ---------------- fused T + B: T = S1@S2^T (kept in LDS), CB = node*(T@node) ----------------
__global__ void k_TB(const short* __restrict__ S1, const short* __restrict__ S2,
                     const short* __restrict__ node_bf, short* __restrict__ CB_bf) {
  const int b = blockIdx.x, head = blockIdx.y;
  const size_t hs = (size_t)head * BS * KN * LQ;
  const int tid = threadIdx.x, lane = tid & 63, m0 = (tid >> 6) * 16;
  const int l15 = lane & 15, g4 = lane >> 4;
  __shared__ __align__(16) short As[64 * 64];   // 8 KB
  __shared__ __align__(16) short Bs[64 * 64];   // 8 KB
  __shared__ __align__(16) short Ts[64 * 64];   // 8 KB, T in A-operand layout
  f32x4 acc[4] = {};
  const short* S1b = S1 + hs + (size_t)b * KN * LQ;
  const short* S2b = S2 + hs + (size_t)b * KN * LQ;
  // phase 1: T = S1 @ S2^T, K=256
  for (int kk = 0; kk < LQ; kk += 64) {
    stage_nat(S1b + kk, LQ, As, tid);
    stage_nat(S2b + kk, LQ, Bs, tid);
    __syncthreads();
    mfma64(As, Bs, acc, lane, m0);
    __syncthreads();
  }
  // write T into LDS (swizzled A-operand layout), bf16
#pragma unroll
  for (int f = 0; f < 4; ++f) {
    int k2 = f * 16 + l15;
#pragma unroll
    for (int e = 0; e < 4; ++e) {
      int c = m0 + g4 * 4 + e;
      *(short*)((char*)Ts + SWZ(c, c * 128 + k2 * 2)) = f2bf(acc[f][e]);
    }
  }
  __syncthreads();
  // phase 2: for each d-tile: Bm = T @ node[:,d0:d0+64]; CB = node * Bm
  const short* nb = node_bf + (size_t)b * KN * BH;
  short* CBh = CB_bf + (size_t)head * BS * KN * BH;
  for (int d0 = 0; d0 < BH; d0 += 64) {
    f32x4 acc2[4] = {};
    stage_tr(nb + d0, BH, Bs, tid);
    __syncthreads();
    mfma64(Ts, Bs, acc2, lane, m0);
#pragma unroll
    for (int f = 0; f < 4; ++f) {
      int d = d0 + f * 16 + l15;
#pragma unroll
      for (int e = 0; e < 4; ++e) {
        int c = m0 + g4 * 4 + e;
        CBh[((size_t)b * KN + c) * BH + d] = f2bf(bf2f(nb[(size_t)c * BH + d]) * acc2[f][e]);
      }
    }
    __syncthreads();
  }
}

// ---------------- proj: feat[32768 x 2048] @ prjT -> H ----------------
// 256row x 128o tile, 512 threads, K=2048, single-buffer gload_lds (R11 proven).
__global__ void k_proj_big(const short* __restrict__ node_bf, const short* __restrict__ A_bf,
                           const short* __restrict__ CA_bf, const short* __restrict__ CB_bf,
                           const short* __restrict__ prjT,
                           short* __restrict__ Hno, short* __restrict__ Hna) {
  const int l = blockIdx.x;            // 512
  const int xcd = l & 7;
  const int u = l >> 3;                // 0..63
  const int head = u & 1;
  const int o0 = ((u >> 1) & 3) * 128;
  const int mt = xcd * 8 + (u >> 3);   // 0..63
  const int r0 = mt * 256;
  const size_t hk = (size_t)head * BS * KN * BH;
  const int tid = threadIdx.x, lane = tid & 63, wave = tid >> 6;  // 8 waves
  const int l15 = lane & 15, g4 = lane >> 4;
  const int m0 = wave * 32;
  __shared__ __align__(16) short As[256 * 64];   // 32 KB
  __shared__ __align__(16) short Bs[128 * 64];   // 16 KB
  f32x4 acc[16] = {};
  const short* segs[4] = {node_bf, A_bf + hk, CA_bf + hk, CB_bf + hk};
  const short* Bpanel = prjT + (size_t)head * BH * 2048 + (size_t)o0 * 2048;
  const int lr = lane >> 3;   // row within 8-row call
  const int ls = lane & 7;    // 16B slot within row

  for (int t = 0; t < 32; ++t) {
    const int kk = t * 64;
    const short* Aseg = segs[kk >> 9] + (size_t)r0 * BH + (kk & 511);
#pragma unroll
    for (int c = 0; c < 4; ++c) {
      int row = wave * 32 + c * 8 + lr;
      int sw = ls ^ ((row ^ (row >> 3)) & 7);
      gl_lds16(Aseg + (size_t)row * BH + sw * 8, As + (wave * 32 + c * 8) * 64);
    }
#pragma unroll
    for (int c = 0; c < 2; ++c) {
      int row = wave * 16 + c * 8 + lr;
      int sw = ls ^ ((row ^ (row >> 3)) & 7);
      gl_lds16(Bpanel + (size_t)row * 2048 + kk + sw * 8, Bs + (wave * 16 + c * 8) * 64);
    }
    __syncthreads();
#pragma unroll
    for (int kb2 = 0; kb2 < 2; ++kb2) {
      int k16 = kb2 * 32 + g4 * 8;
#pragma unroll
      for (int mi = 0; mi < 2; ++mi) {
        int arow = m0 + mi * 16 + l15;
        bf16x8 af = *(const bf16x8*)((const char*)As + SWZ(arow, arow * 128 + k16 * 2));
#pragma unroll
        for (int f = 0; f < 8; ++f) {
          int nrow = f * 16 + l15;
          bf16x8 bfr = *(const bf16x8*)((const char*)Bs + SWZ(nrow, nrow * 128 + k16 * 2));
          acc[mi * 8 + f] = __builtin_amdgcn_mfma_f32_16x16x32_bf16(af, bfr, acc[mi * 8 + f], 0, 0, 0);
        }
      }
    }
    __syncthreads();
  }
  short* H = head ? Hna : Hno;
#pragma unroll
  for (int mi = 0; mi < 2; ++mi) {
#pragma unroll
    for (int f = 0; f < 8; ++f) {
      int o = o0 + f * 16 + l15;
#pragma unroll
      for (int e = 0; e < 4; ++e) {
        int row = r0 + m0 + mi * 16 + g4 * 4 + e;
        H[(size_t)row * BH + o] = f2bf(acc[mi * 8 + f][e]);
      }
    }
  }
}

// Grouped GEMM, full K=1536, no atomics (R8-R11 proven). Tile 64b x 128o, grid 1024.
__global__ void k_blk_mfma(const short* __restrict__ Hno, const short* __restrict__ Hna,
                           const short* __restrict__ node_bf, const float* __restrict__ rew,
                           const short* __restrict__ WT, const float* __restrict__ W,
                           const float* __restrict__ bias, float* __restrict__ out) {
  const int l = blockIdx.x;            // 1024
  const int xcd = l & 7;
  const int idx = l >> 3;              // 0..127
  const int kb = xcd * 8 + (idx & 7);
  const int tile = idx >> 3;           // 0..15
  const int b0 = (tile & 3) * 64, o0 = (tile >> 2) * 128;
  const int tid = threadIdx.x, lane = tid & 63, wave = tid >> 6;
  const int l15 = lane & 15, g4 = lane >> 4;
  const int m0 = wave * 16;
  __shared__ __align__(16) short As[64 * 64];
  __shared__ __align__(16) short Bs[128 * 64];
  f32x4 acc[8] = {};
  const short* segs[3] = {Hno, Hna, node_bf};
  const short* Bpanel = WT + ((size_t)kb * BH + o0) * 1536;
  const int lr = lane >> 3;
  const int ls = lane & 7;

  for (int t = 0; t < 24; ++t) {
    const int kk = t * 64;
    const short* Aseg = segs[kk >> 9] + (size_t)kb * BH + (kk & 511);
#pragma unroll
    for (int c = 0; c < 2; ++c) {
      int row = wave * 16 + c * 8 + lr;
      int sw = ls ^ ((row ^ (row >> 3)) & 7);
      gl_lds16(Aseg + ((size_t)(b0 + row) * KN) * BH + sw * 8,
               As + (wave * 16 + c * 8) * 64);
    }
#pragma unroll
    for (int c = 0; c < 4; ++c) {
      int row = wave * 32 + c * 8 + lr;
      int sw = ls ^ ((row ^ (row >> 3)) & 7);
      gl_lds16(Bpanel + (size_t)row * 1536 + kk + sw * 8,
               Bs + (wave * 32 + c * 8) * 64);
    }
    __syncthreads();
#pragma unroll
    for (int kb2 = 0; kb2 < 2; ++kb2) {
      int k16 = kb2 * 32 + g4 * 8;
      int arow = m0 + l15;
      bf16x8 af = *(const bf16x8*)((const char*)As + SWZ(arow, arow * 128 + k16 * 2));
#pragma unroll
      for (int f = 0; f < 8; ++f) {
        int nrow = f * 16 + l15;
        bf16x8 bfr = *(const bf16x8*)((const char*)Bs + SWZ(nrow, nrow * 128 + k16 * 2));
        acc[f] = __builtin_amdgcn_mfma_f32_16x16x32_bf16(af, bfr, acc[f], 0, 0, 0);
      }
    }
    __syncthreads();
  }
  const float* Wrow = W + (size_t)kb * SUB_IN * BH + (size_t)1536 * BH;
  const float* bkb = bias + kb * BH;
#pragma unroll
  for (int f = 0; f < 8; ++f) {
    int o = o0 + f * 16 + l15;
    float wr = Wrow[o];
    float bv = bkb[o];
#pragma unroll
    for (int e = 0; e < 4; ++e) {
      int bb = b0 + m0 + g4 * 4 + e;
      out[((size_t)bb * KN + kb) * BH + o] = acc[f][e] + rew[bb] * wr + bv;
    }
  }
}

extern "C" void kernel_launch(void* const* d_in, const int* in_sizes, int n_in,
                              void* d_out, int out_size, void* d_ws, size_t ws_size,
                              hipStream_t stream) {
  (void)in_sizes; (void)n_in; (void)out_size; (void)ws_size;
  const float* act   = (const float*)d_in[0];
  const float* obs   = (const float*)d_in[1];
  const float* amask = (const float*)d_in[2];
  const float* omask = (const float*)d_in[3];
  const float* rew   = (const float*)d_in[4];
  const float* node  = (const float*)d_in[5];
  const float* nmask = (const float*)d_in[6];
  const float* w4C_o = (const float*)d_in[7];
  const float* w4Q_o = (const float*)d_in[8];
  const float* w4m_o = (const float*)d_in[9];
  const float* bias_o= (const float*)d_in[10];
  const float* w4C_a = (const float*)d_in[11];
  const float* w4Q_a = (const float*)d_in[12];
  const float* w4m_a = (const float*)d_in[13];
  const float* bias_a= (const float*)d_in[14];
  const float* prj_o = (const float*)d_in[15];
  const float* prj_a = (const float*)d_in[16];
  const float* blkW  = (const float*)d_in[17];
  const float* blkb  = (const float*)d_in[18];
  float* out = (float*)d_out;

  char* wsb = (char*)d_ws;
  auto alloc = [&](size_t bytes) { char* p = wsb; wsb += (bytes + 255) & ~255ull; return p; };
  const size_t NKB = (size_t)BS * KN * BH;   // 8.4M elems
  const size_t NS  = (size_t)BS * KN * LQ;   // 4.2M elems
  short* node_bf = (short*)alloc(NKB * 2);
  short* Cw_o    = (short*)alloc(NKB * 2);
  short* Cw_a    = (short*)alloc(NKB * 2);
  short* prjT    = (short*)alloc((size_t)2 * BH * 2048 * 2);
  short* S1      = (short*)alloc((size_t)2 * NS * 2);
  short* S2      = (short*)alloc((size_t)2 * NS * 2);
  short* A_bf    = (short*)alloc((size_t)2 * NKB * 2);
  short* CA_bf   = (short*)alloc((size_t)2 * NKB * 2);
  short* CB_bf   = (short*)alloc((size_t)2 * NKB * 2);
  short* Hno     = (short*)alloc(NKB * 2);
  short* Hna     = (short*)alloc(NKB * 2);
  short* WT      = (short*)alloc((size_t)KN * BH * 1536 * 2);
  float* cw      = (float*)alloc((size_t)2 * BS * KN * 4);

  k_cvtC2<<<dim3(BS * KN / 4), 256, 0, stream>>>(node, w4C_o, w4C_a, w4m_o, w4m_a,
                                                 node_bf, Cw_o, Cw_a, cw, cw + BS * KN);
  k_prjT<<<dim3(64, 16, 2), 256, 0, stream>>>(prj_o, prj_a, prjT);
  k_WT<<<dim3(48, 16, 64), 256, 0, stream>>>(blkW, WT);
  k_score2<<<dim3(BS, 2), 512, 0, stream>>>(Cw_o, Cw_a, obs, act, w4Q_o, w4Q_a, cw,
                                            bias_o, bias_a, nmask, omask, amask, S1, S2);
  k_gemm_A_mfma<<<dim3(BS, BH / 64, 2), 256, 0, stream>>>(S1, obs, act, node_bf, A_bf, CA_bf);
  k_TB<<<dim3(BS, 2), 256, 0, stream>>>(S1, S2, node_bf, CB_bf);
  k_proj_big<<<dim3(512), 512, 0, stream>>>(node_bf, A_bf, CA_bf, CB_bf, prjT, Hno, Hna);
  k_blk_mfma<<<dim3(1024), 256, 0, stream>>>(Hno, Hna, node_bf, rew, WT, blkW, blkb, out);
}